// Round 8
// baseline (77.433 us; speedup 1.0000x reference)
//
#include <hip/hip_runtime.h>
#include <hip/hip_bf16.h>

#define TDEPTH 6
#define NLEAF 64
#define NGATE 63
#define INF 512
#define OUTF 512
#define BATCH 1024

#define BM 128
#define BN 64
#define SPLITK 16
#define THREADS 256
#define KCH 513   // 512 real i-chunks + 1 virtual bias chunk (x==1, W=pb)
#define XN 32     // real i-planes per block (512/16)

typedef __attribute__((ext_vector_type(4)))  float f32x4;
typedef __attribute__((ext_vector_type(16))) float f32x16;
typedef __attribute__((ext_vector_type(8)))  __bf16 bf16x8;

// ---------------- kernel 1: leaf probabilities ----------------
__global__ __launch_bounds__(256) void leaf_kernel(
    const float* __restrict__ x, const float* __restrict__ gw,
    const float* __restrict__ gb, float* __restrict__ leaf) {
  const int wid = threadIdx.x >> 6, lane = threadIdx.x & 63;
  const int b = blockIdx.x * 4 + wid;
  __shared__ float g[4][NLEAF];
  if (lane < NGATE) {
    const float* xr = x + (size_t)b * INF;
    float a0 = 0.f, a1 = 0.f, a2 = 0.f, a3 = 0.f;
    #pragma unroll 4
    for (int i = 0; i < INF; i += 4) {
      a0 += xr[i + 0] * gw[(i + 0) * NGATE + lane];
      a1 += xr[i + 1] * gw[(i + 1) * NGATE + lane];
      a2 += xr[i + 2] * gw[(i + 2) * NGATE + lane];
      a3 += xr[i + 3] * gw[(i + 3) * NGATE + lane];
    }
    float t = (a0 + a1) + (a2 + a3) + gb[lane];
    g[wid][lane] = 1.0f / (1.0f + __expf(-t));
  }
  __syncthreads();
  float p = 1.0f;
  #pragma unroll
  for (int d = 0; d < TDEPTH; d++) {
    int prefix = lane >> (TDEPTH - 1 - d);
    int node = (1 << d) - 1 + (prefix >> 1);
    float gv = g[wid][node];
    p *= (prefix & 1) ? (1.0f - gv) : gv;
  }
  leaf[(size_t)b * NLEAF + lane] = p;
}

// async 16B global -> LDS (wave-uniform LDS base + lane*16)
__device__ __forceinline__ void gload_lds16(const void* g, void* l) {
  __builtin_amdgcn_global_load_lds(
      (const __attribute__((address_space(1))) void*)g,
      (__attribute__((address_space(3))) void*)l, 16, 0, 0);
}

// ---------------- kernel 2: fused GEMM ----------------
// partial[s][b][o] = sum over K-slice of (x[b,i]*leaf[b,l]) * pw[o,i,l]
// 4 waves, wave tile 32m x 64o, mfma_f32_32x32x16_bf16.
// 40 KB LDS -> 4 blocks/CU (4 independent barrier groups per CU).
// B: f32 via global_load_lds, full-granule (r&15) XOR source pre-swizzle.
__global__ __launch_bounds__(THREADS, 4) void gemm_kernel(
    const float* __restrict__ x, const float* __restrict__ pw,
    const float* __restrict__ pb, const float* __restrict__ leaf,
    float* __restrict__ partial) {
  __shared__ __align__(16) unsigned char Bsm[2][BN * 256];  // 2 x 16 KB (f32)
  __shared__ __align__(16) __bf16 xsm[XN * BM];             // [t][row], 8 KB

  const int tid = threadIdx.x, lane = tid & 63, w = tid >> 6;
  const int lo = lane & 31, half = lane >> 5;

  // XCD-chunked swizzle: 1024 blocks -> 8 chunks of 128; the 8 mb-sharers of
  // a (nb,s) pw-slice are adjacent inside one chunk (one XCD's L2).
  const int L = (blockIdx.x & 7) * 128 + (blockIdx.x >> 3);
  const int mb = L & 7;
  const int rest = L >> 3;            // 0..127 = (nb, s)
  const int nb = rest & 7, s = rest >> 3;
  const int m0 = mb * BM, n0 = nb * BN;
  const int cs = XN * s;
  const int total = XN + ((s == SPLITK - 1) ? 1 : 0);  // +1 bias step on s=15

  // resident leaf fragment: this lane's row (w*32+lo), its k-half: 32 f32
  f32x4 lf[4][2];
  {
    const float* lr = leaf + (size_t)(m0 + w * 32 + lo) * NLEAF + half * 8;
    #pragma unroll
    for (int t4 = 0; t4 < 4; t4++) {
      lf[t4][0] = *(const f32x4*)(lr + t4 * 16);
      lf[t4][1] = *(const f32x4*)(lr + t4 * 16 + 4);
    }
  }

  // stage x slice -> bf16 transposed [t][row]
  {
    const int row = tid >> 1, h = tid & 1;
    const float* src = x + (size_t)(m0 + row) * INF + cs + h * 16;
    #pragma unroll
    for (int c4 = 0; c4 < 4; c4++) {
      f32x4 v = *(const f32x4*)(src + c4 * 4);
      #pragma unroll
      for (int j = 0; j < 4; j++)
        xsm[(h * 16 + c4 * 4 + j) * BM + row] = (__bf16)v[j];
    }
  }

  // staging: round j covers LDS rows j*16+4w..+3; lane -> row r=j*16+4w+lq,
  // granule (lane&15), source pre-swizzled with ^(r&15) (16 granules/row).
  const int lq = lane >> 4;
  const unsigned cg = (unsigned)(lane & 15);
  const unsigned gsw = (cg ^ ((unsigned)(4 * w + lq) & 15)) * 16;
  unsigned pwoff[4], pboff[4];
  #pragma unroll
  for (int j = 0; j < 4; j++) {
    int r = j * 16 + 4 * w + lq;
    pwoff[j] = (unsigned)(n0 + r) * (unsigned)(INF * NLEAF * 4) + gsw;
    pboff[j] = (unsigned)(n0 + r) * (unsigned)(NLEAF * 4) + gsw;
  }
  const char* pwc = (const char*)pw;
  const char* pbc = (const char*)pb;

  auto stage = [&](char* dstb, int t) {
    const int i = cs + t;
    if (i < INF) {
      const char* srcb = pwc + (size_t)i * 256;
      #pragma unroll
      for (int j = 0; j < 4; j++)
        gload_lds16(srcb + pwoff[j], dstb + (j * 16 + 4 * w) * 256);
    } else {  // virtual bias chunk: W = pb
      #pragma unroll
      for (int j = 0; j < 4; j++)
        gload_lds16(pbc + pboff[j], dstb + (j * 16 + 4 * w) * 256);
    }
  };

  f32x16 acc0 = (f32x16)(0.f), acc1 = (f32x16)(0.f);
  const unsigned swz = (unsigned)(lo & 15) << 4;

  auto do_step = [&](const char* bufc, int t) {
    const float xv = (t < XN) ? (float)xsm[t * BM + w * 32 + lo] : 1.0f;
    #pragma unroll
    for (int t4 = 0; t4 < 4; t4++) {
      const unsigned kb = (unsigned)(t4 * 64 + half * 32);
      f32x4 b0a = *(const f32x4*)(bufc + lo * 256 + ((kb) ^ swz));
      f32x4 b0b = *(const f32x4*)(bufc + lo * 256 + ((kb + 16) ^ swz));
      f32x4 b1a = *(const f32x4*)(bufc + (32 + lo) * 256 + ((kb) ^ swz));
      f32x4 b1b = *(const f32x4*)(bufc + (32 + lo) * 256 + ((kb + 16) ^ swz));
      bf16x8 bf0, bf1;
      bf0[0] = (__bf16)b0a[0]; bf0[1] = (__bf16)b0a[1];
      bf0[2] = (__bf16)b0a[2]; bf0[3] = (__bf16)b0a[3];
      bf0[4] = (__bf16)b0b[0]; bf0[5] = (__bf16)b0b[1];
      bf0[6] = (__bf16)b0b[2]; bf0[7] = (__bf16)b0b[3];
      bf1[0] = (__bf16)b1a[0]; bf1[1] = (__bf16)b1a[1];
      bf1[2] = (__bf16)b1a[2]; bf1[3] = (__bf16)b1a[3];
      bf1[4] = (__bf16)b1b[0]; bf1[5] = (__bf16)b1b[1];
      bf1[6] = (__bf16)b1b[2]; bf1[7] = (__bf16)b1b[3];

      f32x4 pa = lf[t4][0] * xv, pbv = lf[t4][1] * xv;
      bf16x8 a;
      a[0] = (__bf16)pa[0]; a[1] = (__bf16)pa[1];
      a[2] = (__bf16)pa[2]; a[3] = (__bf16)pa[3];
      a[4] = (__bf16)pbv[0]; a[5] = (__bf16)pbv[1];
      a[6] = (__bf16)pbv[2]; a[7] = (__bf16)pbv[3];

      acc0 = __builtin_amdgcn_mfma_f32_32x32x16_bf16(a, bf0, acc0, 0, 0, 0);
      acc1 = __builtin_amdgcn_mfma_f32_32x32x16_bf16(a, bf1, acc1, 0, 0, 0);
    }
  };

  char* bA = (char*)&Bsm[0][0];
  char* bB = (char*)&Bsm[1][0];

  // prologue: stage step 0; drain staging + xsm writes; barrier
  stage(bA, 0);
  __builtin_amdgcn_sched_barrier(0);
  asm volatile("s_waitcnt vmcnt(0) lgkmcnt(0)" ::: "memory");
  __builtin_amdgcn_s_barrier();
  __builtin_amdgcn_sched_barrier(0);

  // main loop: 1-ahead staging; residual wait hidden by 3 other resident blocks
  for (int t = 0; t < total; ++t) {
    if (t + 1 < total) stage(bB, t + 1);
    do_step(bA, t);
    __builtin_amdgcn_sched_barrier(0);
    asm volatile("s_waitcnt vmcnt(0)" ::: "memory");
    __builtin_amdgcn_s_barrier();
    __builtin_amdgcn_sched_barrier(0);
    char* tmp = bA; bA = bB; bB = tmp;
  }

  // epilogue: partial[s]; D row = (e&3)+8*(e>>2)+4*half, col = lo
  float* dst = partial + ((size_t)s * BATCH + m0 + w * 32) * OUTF + n0;
  #pragma unroll
  for (int e = 0; e < 16; e++) {
    int row = (e & 3) + 8 * (e >> 2) + 4 * half;
    dst[(size_t)row * OUTF + lo] = acc0[e];
    dst[(size_t)row * OUTF + 32 + lo] = acc1[e];
  }
}

// ---------------- kernel 3: split-K reduce ----------------
__global__ __launch_bounds__(256) void reduce_kernel(
    const float* __restrict__ partial, float* __restrict__ out) {
  size_t e = ((size_t)blockIdx.x * 256 + threadIdx.x) * 4;
  f32x4 sum = (f32x4){0.f, 0.f, 0.f, 0.f};
  #pragma unroll
  for (int s = 0; s < SPLITK; s++)
    sum += *(const f32x4*)(partial + (size_t)s * BATCH * OUTF + e);
  *(f32x4*)(out + e) = sum;
}

extern "C" void kernel_launch(void* const* d_in, const int* in_sizes, int n_in,
                              void* d_out, int out_size, void* d_ws, size_t ws_size,
                              hipStream_t stream) {
  const float* x  = (const float*)d_in[0];
  const float* gw = (const float*)d_in[1];
  const float* gb = (const float*)d_in[2];
  const float* pw = (const float*)d_in[3];
  const float* pb = (const float*)d_in[4];
  float* out = (float*)d_out;

  float* leaf    = (float*)d_ws;                       // 256 KB
  float* partial = (float*)((char*)d_ws + (1 << 20));  // 16 x 2 MB = 32 MB

  leaf_kernel<<<BATCH / 4, 256, 0, stream>>>(x, gw, gb, leaf);
  gemm_kernel<<<8 * 8 * SPLITK, THREADS, 0, stream>>>(x, pw, pb, leaf, partial);
  reduce_kernel<<<(BATCH * OUTF) / (256 * 4), 256, 0, stream>>>(partial, out);
}

// Round 9
// 75.079 us; speedup vs baseline: 1.0314x; 1.0314x over previous
//
#include <hip/hip_runtime.h>
#include <hip/hip_bf16.h>

#define TDEPTH 6
#define NLEAF 64
#define NGATE 63
#define INF 512
#define OUTF 512
#define BATCH 1024

#define BM 128
#define BN 64
#define SPLITK 16
#define THREADS 256
#define XN 32         // real i-planes per block (512/16)
#define PWG (512 * 512 * 8)   // pw granules (16B each)
#define PBG (512 * 8)         // pb granules

typedef __attribute__((ext_vector_type(4)))  float f32x4;
typedef __attribute__((ext_vector_type(16))) float f32x16;
typedef __attribute__((ext_vector_type(8)))  __bf16 bf16x8;

// ---------------- kernel 1: leaf probabilities + pw/pb -> bf16 swizzled ----
// blocks [0,256): leaf.  blocks [256, 256+8208): convert one 16B granule per
// thread, storing granule g of row o at position g^(o&7) (bakes the LDS
// bank-swizzle into the bf16 copy; gemm stages rows linearly).
__global__ __launch_bounds__(256) void prep_kernel(
    const float* __restrict__ x, const float* __restrict__ gw,
    const float* __restrict__ gb, const float* __restrict__ pw,
    const float* __restrict__ pb, float* __restrict__ leaf,
    __bf16* __restrict__ pwb, __bf16* __restrict__ pbb) {
  const int tid = threadIdx.x;
  if (blockIdx.x < 256) {
    const int wid = tid >> 6, lane = tid & 63;
    const int b = blockIdx.x * 4 + wid;
    __shared__ float g[4][NLEAF];
    if (lane < NGATE) {
      const float* xr = x + (size_t)b * INF;
      float a0 = 0.f, a1 = 0.f, a2 = 0.f, a3 = 0.f;
      #pragma unroll 4
      for (int i = 0; i < INF; i += 4) {
        a0 += xr[i + 0] * gw[(i + 0) * NGATE + lane];
        a1 += xr[i + 1] * gw[(i + 1) * NGATE + lane];
        a2 += xr[i + 2] * gw[(i + 2) * NGATE + lane];
        a3 += xr[i + 3] * gw[(i + 3) * NGATE + lane];
      }
      float t = (a0 + a1) + (a2 + a3) + gb[lane];
      g[wid][lane] = 1.0f / (1.0f + __expf(-t));
    }
    __syncthreads();
    float p = 1.0f;
    #pragma unroll
    for (int d = 0; d < TDEPTH; d++) {
      int prefix = lane >> (TDEPTH - 1 - d);
      int node = (1 << d) - 1 + (prefix >> 1);
      float gv = g[wid][node];
      p *= (prefix & 1) ? (1.0f - gv) : gv;
    }
    leaf[(size_t)b * NLEAF + lane] = p;
  } else {
    const unsigned G = (blockIdx.x - 256) * 256 + tid;
    const float* src;
    char* dst;
    if (G < PWG) {
      unsigned o = G >> 12, rem = G & 4095, i = rem >> 3, gg = rem & 7;
      src = pw + ((size_t)(o * 512 + i) * 64 + gg * 8);
      dst = (char*)pwb + ((size_t)(o * 512 + i) * 8 + (gg ^ (o & 7))) * 16;
    } else {
      unsigned G2 = G - PWG;
      unsigned o = G2 >> 3, gg = G2 & 7;
      src = pb + ((size_t)o * 64 + gg * 8);
      dst = (char*)pbb + ((size_t)o * 8 + (gg ^ (o & 7))) * 16;
    }
    f32x4 a = *(const f32x4*)src, b = *(const f32x4*)(src + 4);
    bf16x8 wv;
    wv[0] = (__bf16)a[0]; wv[1] = (__bf16)a[1];
    wv[2] = (__bf16)a[2]; wv[3] = (__bf16)a[3];
    wv[4] = (__bf16)b[0]; wv[5] = (__bf16)b[1];
    wv[6] = (__bf16)b[2]; wv[7] = (__bf16)b[3];
    *(bf16x8*)dst = wv;
  }
}

// async 16B global -> LDS (wave-uniform LDS base + lane*16)
__device__ __forceinline__ void gload_lds16(const void* g, void* l) {
  __builtin_amdgcn_global_load_lds(
      (const __attribute__((address_space(1))) void*)g,
      (__attribute__((address_space(3))) void*)l, 16, 0, 0);
}

// ---------------- kernel 2: fused GEMM (bf16 B, counted vmcnt) ----------------
// partial[s][b][o] = sum over K-slice of (x[b,i]*leaf[b,l]) * pw[o,i,l]
// 4 waves, wave tile 32m x 64o, mfma_f32_32x32x16_bf16. B already bf16 +
// swizzled in HBM: staging = linear 8KB row-copy via global_load_lds (2/wave),
// 3 LDS buffers, stage t+2 at top, s_waitcnt vmcnt(2) (never 0) + barrier.
__global__ __launch_bounds__(THREADS, 4) void gemm_kernel(
    const __bf16* __restrict__ pwb, const __bf16* __restrict__ pbb,
    const float* __restrict__ x, const float* __restrict__ leaf,
    float* __restrict__ partial) {
  __shared__ __align__(16) __bf16 Bsm[3][BN * 64];   // 3 x 8 KB
  __shared__ __align__(16) __bf16 xsm[XN * BM];      // [t][row], 8 KB

  const int tid = threadIdx.x, lane = tid & 63, w = tid >> 6;
  const int lo = lane & 31, half = lane >> 5;

  // XCD-chunked swizzle: 1024 blocks -> 8 chunks of 128; the 8 mb-sharers of
  // a (nb,s) pw-slice are adjacent inside one chunk (one XCD's L2).
  const int L = (blockIdx.x & 7) * 128 + (blockIdx.x >> 3);
  const int mb = L & 7;
  const int rest = L >> 3;
  const int nb = rest & 7, s = rest >> 3;
  const int m0 = mb * BM, n0 = nb * BN;
  const int cs = XN * s;
  const int total = XN + ((s == SPLITK - 1) ? 1 : 0);  // +1 bias step on s=15

  // resident leaf fragment: row (w*32+lo), k-half: 32 f32
  f32x4 lf[4][2];
  {
    const float* lr = leaf + (size_t)(m0 + w * 32 + lo) * NLEAF + half * 8;
    #pragma unroll
    for (int t4 = 0; t4 < 4; t4++) {
      lf[t4][0] = *(const f32x4*)(lr + t4 * 16);
      lf[t4][1] = *(const f32x4*)(lr + t4 * 16 + 4);
    }
  }

  // stage x slice -> bf16 transposed [t][row]
  {
    const int row = tid >> 1, h = tid & 1;
    const float* src = x + (size_t)(m0 + row) * INF + cs + h * 16;
    #pragma unroll
    for (int c4 = 0; c4 < 4; c4++) {
      f32x4 v = *(const f32x4*)(src + c4 * 4);
      #pragma unroll
      for (int j = 0; j < 4; j++)
        xsm[(h * 16 + c4 * 4 + j) * BM + row] = (__bf16)v[j];
    }
  }

  // staging: linear copy of 64 bf16 rows (128B each). Round j: granules
  // [j*256 + w*64 + lane]; row r = granule>>3, pos = lane&7 (swizzle already
  // baked into pwb by prep_kernel).
  size_t pwoff[2], pboff[2];
  #pragma unroll
  for (int j = 0; j < 2; j++) {
    int r = j * 32 + w * 8 + (lane >> 3);
    pwoff[j] = (size_t)(n0 + r) * (512 * 128) + (size_t)(lane & 7) * 16;
    pboff[j] = (size_t)(n0 + r) * 128 + (size_t)(lane & 7) * 16;
  }
  const char* pwc = (const char*)pwb;
  const char* pbc = (const char*)pbb;

  auto stage = [&](char* dstb, int t) {
    const int i = cs + t;
    if (i < INF) {
      #pragma unroll
      for (int j = 0; j < 2; j++)
        gload_lds16(pwc + pwoff[j] + (size_t)i * 128,
                    dstb + j * 4096 + w * 1024);
    } else {  // virtual bias plane: W = pb
      #pragma unroll
      for (int j = 0; j < 2; j++)
        gload_lds16(pbc + pboff[j], dstb + j * 4096 + w * 1024);
    }
  };

  f32x16 acc0 = (f32x16)(0.f), acc1 = (f32x16)(0.f);
  const unsigned swz = (unsigned)(lo & 7) << 4;

  auto do_step = [&](const char* bufc, int t) {
    const float xv = (t < XN) ? (float)xsm[t * BM + w * 32 + lo] : 1.0f;
    #pragma unroll
    for (int t4 = 0; t4 < 4; t4++) {
      const unsigned kb = ((unsigned)(t4 * 32 + half * 16)) ^ swz;
      bf16x8 bf0 = *(const bf16x8*)(bufc + lo * 128 + kb);
      bf16x8 bf1 = *(const bf16x8*)(bufc + (32 + lo) * 128 + kb);
      f32x4 pa = lf[t4][0] * xv, pbv = lf[t4][1] * xv;
      bf16x8 a;
      a[0] = (__bf16)pa[0]; a[1] = (__bf16)pa[1];
      a[2] = (__bf16)pa[2]; a[3] = (__bf16)pa[3];
      a[4] = (__bf16)pbv[0]; a[5] = (__bf16)pbv[1];
      a[6] = (__bf16)pbv[2]; a[7] = (__bf16)pbv[3];
      acc0 = __builtin_amdgcn_mfma_f32_32x32x16_bf16(a, bf0, acc0, 0, 0, 0);
      acc1 = __builtin_amdgcn_mfma_f32_32x32x16_bf16(a, bf1, acc1, 0, 0, 0);
    }
  };

  char* bA = (char*)&Bsm[0][0];
  char* bB = (char*)&Bsm[1][0];
  char* bC = (char*)&Bsm[2][0];

  // prologue: stage 0,1; wait stage0 (keep stage1's 2 loads in flight)
  stage(bA, 0);
  stage(bB, 1);
  __builtin_amdgcn_sched_barrier(0);
  asm volatile("s_waitcnt vmcnt(2) lgkmcnt(0)" ::: "memory");
  __builtin_amdgcn_s_barrier();
  __builtin_amdgcn_sched_barrier(0);

  // main loop: counted vmcnt(2) — stage(t+2) stays in flight across barrier
  for (int t = 0; t < total - 2; ++t) {
    stage(bC, t + 2);
    do_step(bA, t);
    __builtin_amdgcn_sched_barrier(0);
    asm volatile("s_waitcnt vmcnt(2)" ::: "memory");
    __builtin_amdgcn_s_barrier();
    __builtin_amdgcn_sched_barrier(0);
    char* tmp = bA; bA = bB; bB = bC; bC = tmp;
  }
  // tail: drain fully, compute last two steps
  do_step(bA, total - 2);
  __builtin_amdgcn_sched_barrier(0);
  asm volatile("s_waitcnt vmcnt(0)" ::: "memory");
  __builtin_amdgcn_s_barrier();
  __builtin_amdgcn_sched_barrier(0);
  do_step(bB, total - 1);

  // epilogue: partial[s]; D row = (e&3)+8*(e>>2)+4*half, col = lo
  float* dst = partial + ((size_t)s * BATCH + m0 + w * 32) * OUTF + n0;
  #pragma unroll
  for (int e = 0; e < 16; e++) {
    int row = (e & 3) + 8 * (e >> 2) + 4 * half;
    dst[(size_t)row * OUTF + lo] = acc0[e];
    dst[(size_t)row * OUTF + 32 + lo] = acc1[e];
  }
}

// ---------------- kernel 3: split-K reduce ----------------
__global__ __launch_bounds__(256) void reduce_kernel(
    const float* __restrict__ partial, float* __restrict__ out) {
  size_t e = ((size_t)blockIdx.x * 256 + threadIdx.x) * 4;
  f32x4 sum = (f32x4){0.f, 0.f, 0.f, 0.f};
  #pragma unroll
  for (int s = 0; s < SPLITK; s++)
    sum += *(const f32x4*)(partial + (size_t)s * BATCH * OUTF + e);
  *(f32x4*)(out + e) = sum;
}

extern "C" void kernel_launch(void* const* d_in, const int* in_sizes, int n_in,
                              void* d_out, int out_size, void* d_ws, size_t ws_size,
                              hipStream_t stream) {
  const float* x  = (const float*)d_in[0];
  const float* gw = (const float*)d_in[1];
  const float* gb = (const float*)d_in[2];
  const float* pw = (const float*)d_in[3];
  const float* pb = (const float*)d_in[4];
  float* out = (float*)d_out;

  float*  leaf    = (float*)d_ws;                                  // 256 KB
  __bf16* pbb     = (__bf16*)((char*)d_ws + (256 << 10));          // 64 KB
  __bf16* pwb     = (__bf16*)((char*)d_ws + (1 << 20));            // 32 MB
  float*  partial = (float*)((char*)d_ws + (1 << 20) + (32 << 20)); // 32 MB

  prep_kernel<<<256 + (PWG + PBG) / 256, 256, 0, stream>>>(
      x, gw, gb, pw, pb, leaf, pwb, pbb);
  gemm_kernel<<<8 * 8 * SPLITK, THREADS, 0, stream>>>(pwb, pbb, x, leaf, partial);
  reduce_kernel<<<(BATCH * OUTF) / (256 * 4), 256, 0, stream>>>(partial, out);
}

// Round 10
// 70.479 us; speedup vs baseline: 1.0987x; 1.0653x over previous
//
#include <hip/hip_runtime.h>
#include <hip/hip_bf16.h>

#define TDEPTH 6
#define NLEAF 64
#define NGATE 63
#define INF 512
#define OUTF 512
#define BATCH 1024

#define BM 256
#define BN 64
#define THREADS 256

typedef __attribute__((ext_vector_type(4)))  float f32x4;
typedef __attribute__((ext_vector_type(16))) float f32x16;
typedef __attribute__((ext_vector_type(8)))  __bf16 bf16x8;

__device__ __forceinline__ bf16x8 pack8(f32x4 a, f32x4 b) {
  bf16x8 w;
  w[0] = (__bf16)a[0]; w[1] = (__bf16)a[1];
  w[2] = (__bf16)a[2]; w[3] = (__bf16)a[3];
  w[4] = (__bf16)b[0]; w[5] = (__bf16)b[1];
  w[6] = (__bf16)b[2]; w[7] = (__bf16)b[3];
  return w;
}

// ---------------- kernel 1: leaf probs + pwb pack ----------------
// blocks [0,256): leaf. blocks [256,8448): pack pw -> bf16 pwb with layout
// pwb[o][ipair][pos], pos = g ^ (o&15), g = (i&1)*8 + kg  (i-pair per 256B
// row, 16-granule XOR -> conflict-free ds_read_b128 with swz=(lo&15)<<4).
__global__ __launch_bounds__(256) void prep_kernel(
    const float* __restrict__ x, const float* __restrict__ gw,
    const float* __restrict__ gb, const float* __restrict__ pw,
    float* __restrict__ leaf, __bf16* __restrict__ pwb) {
  const int tid = threadIdx.x;
  if (blockIdx.x < 256) {
    const int wid = tid >> 6, lane = tid & 63;
    const int b = blockIdx.x * 4 + wid;
    __shared__ float g[4][NLEAF];
    if (lane < NGATE) {
      const float* xr = x + (size_t)b * INF;
      float a0 = 0.f, a1 = 0.f, a2 = 0.f, a3 = 0.f;
      #pragma unroll 4
      for (int i = 0; i < INF; i += 4) {
        a0 += xr[i + 0] * gw[(i + 0) * NGATE + lane];
        a1 += xr[i + 1] * gw[(i + 1) * NGATE + lane];
        a2 += xr[i + 2] * gw[(i + 2) * NGATE + lane];
        a3 += xr[i + 3] * gw[(i + 3) * NGATE + lane];
      }
      float t = (a0 + a1) + (a2 + a3) + gb[lane];
      g[wid][lane] = 1.0f / (1.0f + __expf(-t));
    }
    __syncthreads();
    float p = 1.0f;
    #pragma unroll
    for (int d = 0; d < TDEPTH; d++) {
      int prefix = lane >> (TDEPTH - 1 - d);
      int node = (1 << d) - 1 + (prefix >> 1);
      float gv = g[wid][node];
      p *= (prefix & 1) ? (1.0f - gv) : gv;
    }
    leaf[(size_t)b * NLEAF + lane] = p;
  } else {
    const unsigned G = (blockIdx.x - 256) * 256 + tid;  // < 2^21
    const unsigned o = G >> 12, rem = G & 4095;
    const unsigned ipair = rem >> 4, p = rem & 15;
    const unsigned g = p ^ (o & 15);
    const unsigned i = ipair * 2 + (g >> 3), kg = g & 7;
    const float* src = pw + (((size_t)o * INF + i) * NLEAF + kg * 8);
    f32x4 a = *(const f32x4*)src, b = *(const f32x4*)(src + 4);
    *(bf16x8*)((char*)pwb + (((size_t)o << 16) + (ipair << 8) + (p << 4))) =
        pack8(a, b);
  }
}

// async 16B global -> LDS (wave-uniform LDS base; lane*16 implicit)
__device__ __forceinline__ void gload_lds16(const void* g, void* l) {
  __builtin_amdgcn_global_load_lds(
      (const __attribute__((address_space(1))) void*)g,
      (__attribute__((address_space(3))) void*)l, 16, 0, 0);
}

// ---------------- kernel 2: fused GEMM ----------------
// partial[s][b][o] = sum over K-slice of (x[b,i]*leaf[b,l]) * pw[o,i,l]
// 4 waves, wave tile 64m x 64o (acc 2x2 f32x16), mfma_f32_32x32x16_bf16.
// B: bf16, 2 planes per 256B LDS row, 16-granule XOR baked by prep ->
// conflict-free reads. 3 buffers, counted s_waitcnt vmcnt(4) (never 0).
template <int S>
__global__ __launch_bounds__(THREADS, 2) void gemm_kernel(
    const __bf16* __restrict__ pwb, const float* __restrict__ pb,
    const float* __restrict__ x, const float* __restrict__ leaf,
    float* __restrict__ partial) {
  constexpr int NSTEP = 256 / S;   // ipair steps per block
  constexpr int NPL = 512 / S;     // planes per block
  __shared__ __align__(16) __bf16 Bsm[3][BN * 128];  // 3 x 16 KB
  __shared__ __align__(16) __bf16 xsm[NPL][BM];      // [plane][row]

  const int tid = threadIdx.x, lane = tid & 63, w = tid >> 6;
  const int lo = lane & 31, half = lane >> 5;

  // XCD-chunked swizzle: the 4 mb-sharers of a (nb,s) slice are adjacent
  // inside one XCD's contiguous chunk.
  const int nwg = 4 * 8 * S;
  const int L = (blockIdx.x & 7) * (nwg / 8) + (blockIdx.x >> 3);
  const int mb = L & 3;
  const int rest = L >> 2;
  const int nb = rest & 7, s = rest >> 3;
  const int m0 = mb * BM, n0 = nb * BN;
  const int ip0 = s * NSTEP;       // base ipair
  const int cs = s * NPL;          // base plane

  // resident leaf fragments: 2 m-subtiles x 32 f32 (this lane's k-half)
  f32x4 lf[2][4][2];
  #pragma unroll
  for (int mt = 0; mt < 2; mt++) {
    const float* lr =
        leaf + (size_t)(m0 + w * 64 + mt * 32 + lo) * NLEAF + half * 8;
    #pragma unroll
    for (int t4 = 0; t4 < 4; t4++) {
      lf[mt][t4][0] = *(const f32x4*)(lr + t4 * 16);
      lf[mt][t4][1] = *(const f32x4*)(lr + t4 * 16 + 4);
    }
  }

  // stage x slice -> bf16 [plane][row]
  {
    const float* src = x + (size_t)(m0 + tid) * INF + cs;
    #pragma unroll
    for (int c4 = 0; c4 < NPL / 4; c4++) {
      f32x4 v = *(const f32x4*)(src + c4 * 4);
      #pragma unroll
      for (int j = 0; j < 4; j++) xsm[c4 * 4 + j][tid] = (__bf16)v[j];
    }
  }

  // staging offsets: round j covers LDS rows j*16+w*4 .. +3 (1 KB/wave/round)
  size_t pwoff[4];
  #pragma unroll
  for (int j = 0; j < 4; j++) {
    int r = j * 16 + w * 4 + (lane >> 4);
    pwoff[j] = ((size_t)(n0 + r) << 16) + ((unsigned)(lane & 15) << 4);
  }
  const char* pwc = (const char*)pwb;

  auto stage = [&](char* dstb, int t) {
    const char* srcb = pwc + ((size_t)(ip0 + t) << 8);
    #pragma unroll
    for (int j = 0; j < 4; j++)
      gload_lds16(srcb + pwoff[j], dstb + j * 4096 + w * 1024);
  };

  f32x16 acc00 = (f32x16)(0.f), acc01 = (f32x16)(0.f);
  f32x16 acc10 = (f32x16)(0.f), acc11 = (f32x16)(0.f);
  const unsigned swz = (unsigned)(lo & 15) << 4;

  auto do_step = [&](const char* bufc, int t) {
    const float xv00 = (float)xsm[2 * t][w * 64 + lo];
    const float xv01 = (float)xsm[2 * t + 1][w * 64 + lo];
    const float xv10 = (float)xsm[2 * t][w * 64 + 32 + lo];
    const float xv11 = (float)xsm[2 * t + 1][w * 64 + 32 + lo];
    #pragma unroll
    for (int pl = 0; pl < 2; pl++) {
      const float x0 = pl ? xv01 : xv00;
      const float x1 = pl ? xv11 : xv10;
      #pragma unroll
      for (int t4 = 0; t4 < 4; t4++) {
        const unsigned kb = ((unsigned)(pl * 128 + t4 * 32 + half * 16)) ^ swz;
        bf16x8 bf0 = *(const bf16x8*)(bufc + lo * 256 + kb);
        bf16x8 bf1 = *(const bf16x8*)(bufc + (32 + lo) * 256 + kb);
        f32x4 p0a = lf[0][t4][0] * x0, p0b = lf[0][t4][1] * x0;
        f32x4 p1a = lf[1][t4][0] * x1, p1b = lf[1][t4][1] * x1;
        bf16x8 a0 = pack8(p0a, p0b);
        bf16x8 a1 = pack8(p1a, p1b);
        acc00 = __builtin_amdgcn_mfma_f32_32x32x16_bf16(a0, bf0, acc00, 0, 0, 0);
        acc01 = __builtin_amdgcn_mfma_f32_32x32x16_bf16(a0, bf1, acc01, 0, 0, 0);
        acc10 = __builtin_amdgcn_mfma_f32_32x32x16_bf16(a1, bf0, acc10, 0, 0, 0);
        acc11 = __builtin_amdgcn_mfma_f32_32x32x16_bf16(a1, bf1, acc11, 0, 0, 0);
      }
    }
  };

  char* bA = (char*)&Bsm[0][0];
  char* bB = (char*)&Bsm[1][0];
  char* bC = (char*)&Bsm[2][0];

  // prologue: stage 0,1; full drain once (x ds_writes + stages); barrier
  stage(bA, 0);
  stage(bB, 1);
  __builtin_amdgcn_sched_barrier(0);
  asm volatile("s_waitcnt vmcnt(0) lgkmcnt(0)" ::: "memory");
  __builtin_amdgcn_s_barrier();
  __builtin_amdgcn_sched_barrier(0);

  // main loop: counted vmcnt(4) — stage(t+2)'s 4 loads stay in flight
  for (int t = 0; t < NSTEP - 2; ++t) {
    stage(bC, t + 2);
    do_step(bA, t);
    __builtin_amdgcn_sched_barrier(0);
    asm volatile("s_waitcnt vmcnt(4) lgkmcnt(0)" ::: "memory");
    __builtin_amdgcn_s_barrier();
    __builtin_amdgcn_sched_barrier(0);
    char* tmp = bA; bA = bB; bB = bC; bC = tmp;
  }
  do_step(bA, NSTEP - 2);
  __builtin_amdgcn_sched_barrier(0);
  asm volatile("s_waitcnt vmcnt(0) lgkmcnt(0)" ::: "memory");
  __builtin_amdgcn_s_barrier();
  __builtin_amdgcn_sched_barrier(0);
  do_step(bB, NSTEP - 1);

  // bias contribution (s == S-1 only): A = leaf (x==1), W = pb read direct
  if (s == S - 1) {
    #pragma unroll
    for (int t4 = 0; t4 < 4; t4++) {
      bf16x8 a0 = pack8(lf[0][t4][0], lf[0][t4][1]);
      bf16x8 a1 = pack8(lf[1][t4][0], lf[1][t4][1]);
      #pragma unroll
      for (int nt = 0; nt < 2; nt++) {
        const float* pr =
            pb + (size_t)(n0 + nt * 32 + lo) * NLEAF + t4 * 16 + half * 8;
        f32x4 c0 = *(const f32x4*)pr, c1 = *(const f32x4*)(pr + 4);
        bf16x8 bb = pack8(c0, c1);
        if (nt == 0) {
          acc00 = __builtin_amdgcn_mfma_f32_32x32x16_bf16(a0, bb, acc00, 0, 0, 0);
          acc10 = __builtin_amdgcn_mfma_f32_32x32x16_bf16(a1, bb, acc10, 0, 0, 0);
        } else {
          acc01 = __builtin_amdgcn_mfma_f32_32x32x16_bf16(a0, bb, acc01, 0, 0, 0);
          acc11 = __builtin_amdgcn_mfma_f32_32x32x16_bf16(a1, bb, acc11, 0, 0, 0);
        }
      }
    }
  }

  // epilogue: partial[s]; D row = (e&3)+8*(e>>2)+4*half, col = lo
  #pragma unroll
  for (int mt = 0; mt < 2; mt++) {
    float* dst =
        partial + ((size_t)s * BATCH + m0 + w * 64 + mt * 32) * OUTF + n0;
    #pragma unroll
    for (int e = 0; e < 16; e++) {
      int row = (e & 3) + 8 * (e >> 2) + 4 * half;
      if (mt == 0) {
        dst[(size_t)row * OUTF + lo] = acc00[e];
        dst[(size_t)row * OUTF + 32 + lo] = acc01[e];
      } else {
        dst[(size_t)row * OUTF + lo] = acc10[e];
        dst[(size_t)row * OUTF + 32 + lo] = acc11[e];
      }
    }
  }
}

// ---------------- kernel 3: split-K reduce ----------------
template <int S>
__global__ __launch_bounds__(256) void reduce_kernel(
    const float* __restrict__ partial, float* __restrict__ out) {
  size_t e = ((size_t)blockIdx.x * 256 + threadIdx.x) * 4;
  f32x4 sum = (f32x4){0.f, 0.f, 0.f, 0.f};
  #pragma unroll
  for (int s = 0; s < S; s++)
    sum += *(const f32x4*)(partial + (size_t)s * BATCH * OUTF + e);
  *(f32x4*)(out + e) = sum;
}

extern "C" void kernel_launch(void* const* d_in, const int* in_sizes, int n_in,
                              void* d_out, int out_size, void* d_ws, size_t ws_size,
                              hipStream_t stream) {
  const float* x  = (const float*)d_in[0];
  const float* gw = (const float*)d_in[1];
  const float* gb = (const float*)d_in[2];
  const float* pw = (const float*)d_in[3];
  const float* pb = (const float*)d_in[4];
  float* out = (float*)d_out;

  float*  leaf    = (float*)d_ws;                        // 256 KB
  __bf16* pwb     = (__bf16*)((char*)d_ws + (1 << 20));  // 32 MB
  float*  partial = (float*)((char*)d_ws + (33ull << 20));

  prep_kernel<<<256 + 8192, 256, 0, stream>>>(x, gw, gb, pw, leaf, pwb);

  const size_t need16 = (33ull << 20) + (size_t)16 * BATCH * OUTF * 4;
  if (ws_size >= need16) {
    gemm_kernel<16><<<4 * 8 * 16, THREADS, 0, stream>>>(pwb, pb, x, leaf, partial);
    reduce_kernel<16><<<(BATCH * OUTF) / (256 * 4), 256, 0, stream>>>(partial, out);
  } else {
    gemm_kernel<8><<<4 * 8 * 8, THREADS, 0, stream>>>(pwb, pb, x, leaf, partial);
    reduce_kernel<8><<<(BATCH * OUTF) / (256 * 4), 256, 0, stream>>>(partial, out);
  }
}